// Round 1
// baseline (903.709 us; speedup 1.0000x reference)
//
#include <hip/hip_runtime.h>
#include <math.h>

// Fused: L2-normalize(emb row) -> seg = searchsorted(ptr[1:], row, right)
//        -> sim[row] = scale * sum_h emb_n[row,h]*d[h]*summary[seg,h]
//
// Layout: one emb row (H=128 floats = 512B) per 32-lane half-wave.
//   lane loads float4 (16B) -> coalesced. Butterfly shfl_xor reduce within
//   the 32-lane half (masks 16..1 never cross the half boundary).
// Memory-bound: ~520 MB HBM traffic -> ~83us roofline at 6.3 TB/s.

#define HDIM 128
#define NEPS 1e-12f

__global__ __launch_bounds__(256) void sim_kernel(
    const float* __restrict__ emb,
    const float* __restrict__ summary,
    const int* __restrict__ ptr,   // B+1 entries (int32; JAX x64 off)
    const float* __restrict__ dvec,
    const float* __restrict__ scale,
    float* __restrict__ out,
    int N, int B)
{
    const int tid  = blockIdx.x * blockDim.x + threadIdx.x;
    const int wave = tid >> 6;       // global wave id
    const int lane = tid & 63;
    const int half = lane >> 5;      // which row of the pair
    const int l    = lane & 31;      // lane within the 32-lane row group

    const long long row = (long long)wave * 2 + half;
    if (row >= N) return;

    // seg = first j in [0,B) with ptr[1+j] > row  (== searchsorted right)
    int lo = 0, hi = B;
    while (lo < hi) {
        int mid = (lo + hi) >> 1;
        if (ptr[1 + mid] <= (int)row) lo = mid + 1; else hi = mid;
    }
    const int seg = lo;

    const float4* e4 = (const float4*)(emb + row * HDIM);
    const float4* s4 = (const float4*)(summary + (long long)seg * HDIM);
    const float4* d4 = (const float4*)dvec;

    const float4 e  = e4[l];
    const float4 s  = s4[l];
    const float4 dd = d4[l];

    float sumsq = e.x * e.x + e.y * e.y + e.z * e.z + e.w * e.w;
    float dot   = e.x * dd.x * s.x + e.y * dd.y * s.y
                + e.z * dd.z * s.z + e.w * dd.w * s.w;

    // butterfly reduce across the 32-lane half (xor masks < 32 stay in-half)
    #pragma unroll
    for (int m = 16; m >= 1; m >>= 1) {
        sumsq += __shfl_xor(sumsq, m, 64);
        dot   += __shfl_xor(dot,   m, 64);
    }

    if (l == 0) {
        const float nrm = sqrtf(sumsq);
        out[row] = dot / fmaxf(nrm, NEPS) * scale[0];
    }
}

extern "C" void kernel_launch(void* const* d_in, const int* in_sizes, int n_in,
                              void* d_out, int out_size, void* d_ws, size_t ws_size,
                              hipStream_t stream) {
    const float* emb     = (const float*)d_in[0];
    const float* summary = (const float*)d_in[1];
    const int*   ptr     = (const int*)d_in[2];
    const float* dvec    = (const float*)d_in[3];
    const float* scale   = (const float*)d_in[4];
    float*       out     = (float*)d_out;

    const int Hn = in_sizes[3];            // 128
    const int N  = in_sizes[0] / Hn;       // 1048576
    const int B  = in_sizes[1] / Hn;       // 1024

    // 2 rows per wave, 4 waves per block -> 8 rows per block
    const int blocks = (N + 7) / 8;
    sim_kernel<<<blocks, 256, 0, stream>>>(emb, summary, ptr, dvec, scale,
                                           out, N, B);
}

// Round 2
// 679.886 us; speedup vs baseline: 1.3292x; 1.3292x over previous
//
#include <hip/hip_runtime.h>
#include <math.h>

// Fused: L2-normalize(emb row) -> sim[row] = scale * <emb_n[row], d*summary[seg[row]]>
//
// R2 restructure (R1 was VALU/latency-bound at 380us, 9% HBM):
//  - seg[] precomputed by scatter over segments (no per-row binary search)
//  - sd[] = summary * d * scale precomputed (B*H = 512KB)
//  - 8 lanes per row, lane holds 4x float4 -> 3-step shuffle reduce per 8 rows
// Expect main kernel ~memory-limited: ~520MB logical traffic, L3-assisted.

#define HDIM 128
#define NEPS 1e-12f

// ---- prep 1: seg[row] = s for row in [ptr[s], ptr[s+1]) ----
__global__ void seg_fill(const int* __restrict__ ptr, int* __restrict__ seg) {
    const int s  = blockIdx.x;
    const int lo = ptr[s], hi = ptr[s + 1];
    for (int i = lo + threadIdx.x; i < hi; i += blockDim.x)
        seg[i] = s;
}

// ---- prep 2: sd = summary * d * scale ----
__global__ void sd_fill(const float* __restrict__ summary,
                        const float* __restrict__ dvec,
                        const float* __restrict__ scale,
                        float* __restrict__ sd, int total) {
    const int i = blockIdx.x * blockDim.x + threadIdx.x;
    if (i < total) sd[i] = summary[i] * dvec[i & (HDIM - 1)] * scale[0];
}

// ---- main: 8 lanes per row ----
__global__ __launch_bounds__(256) void sim_main(
    const float* __restrict__ emb,
    const float* __restrict__ sd,
    const int* __restrict__ seg,
    float* __restrict__ out, int N)
{
    const int tid = blockIdx.x * blockDim.x + threadIdx.x;
    const int sub = tid & 7;                  // lane within 8-lane row group
    const long long row = (long long)(tid >> 3);
    if (row >= N) return;

    const int s = seg[row];
    const float4* e4 = (const float4*)(emb + row * (long long)HDIM);
    const float4* w4 = (const float4*)(sd + (long long)s * HDIM);

    float sumsq = 0.f, dot = 0.f;
    #pragma unroll
    for (int j = 0; j < 4; ++j) {
        const float4 e = e4[sub + 8 * j];
        const float4 w = w4[sub + 8 * j];
        sumsq = fmaf(e.x, e.x, sumsq); sumsq = fmaf(e.y, e.y, sumsq);
        sumsq = fmaf(e.z, e.z, sumsq); sumsq = fmaf(e.w, e.w, sumsq);
        dot   = fmaf(e.x, w.x, dot);   dot   = fmaf(e.y, w.y, dot);
        dot   = fmaf(e.z, w.z, dot);   dot   = fmaf(e.w, w.w, dot);
    }
    // reduce across the 8-lane group (xor masks 4,2,1 stay in-group)
    #pragma unroll
    for (int m = 4; m >= 1; m >>= 1) {
        sumsq += __shfl_xor(sumsq, m, 64);
        dot   += __shfl_xor(dot,   m, 64);
    }
    if (sub == 0)
        out[row] = dot / fmaxf(sqrtf(sumsq), NEPS);
}

// ---- fallback (R1 kernel) if ws too small ----
__global__ __launch_bounds__(256) void sim_fallback(
    const float* __restrict__ emb, const float* __restrict__ summary,
    const int* __restrict__ ptr, const float* __restrict__ dvec,
    const float* __restrict__ scale, float* __restrict__ out, int N, int B)
{
    const int tid  = blockIdx.x * blockDim.x + threadIdx.x;
    const int lane = tid & 63;
    const int half = lane >> 5;
    const int l    = lane & 31;
    const long long row = (long long)(tid >> 6) * 2 + half;
    if (row >= N) return;
    int lo = 0, hi = B;
    while (lo < hi) {
        int mid = (lo + hi) >> 1;
        if (ptr[1 + mid] <= (int)row) lo = mid + 1; else hi = mid;
    }
    const float4* e4 = (const float4*)(emb + row * HDIM);
    const float4* s4 = (const float4*)(summary + (long long)lo * HDIM);
    const float4* d4 = (const float4*)dvec;
    const float4 e = e4[l], s = s4[l], dd = d4[l];
    float sumsq = e.x*e.x + e.y*e.y + e.z*e.z + e.w*e.w;
    float dot   = e.x*dd.x*s.x + e.y*dd.y*s.y + e.z*dd.z*s.z + e.w*dd.w*s.w;
    #pragma unroll
    for (int m = 16; m >= 1; m >>= 1) {
        sumsq += __shfl_xor(sumsq, m, 64);
        dot   += __shfl_xor(dot,   m, 64);
    }
    if (l == 0)
        out[row] = dot / fmaxf(sqrtf(sumsq), NEPS) * scale[0];
}

extern "C" void kernel_launch(void* const* d_in, const int* in_sizes, int n_in,
                              void* d_out, int out_size, void* d_ws, size_t ws_size,
                              hipStream_t stream) {
    const float* emb     = (const float*)d_in[0];
    const float* summary = (const float*)d_in[1];
    const int*   ptr     = (const int*)d_in[2];
    const float* dvec    = (const float*)d_in[3];
    const float* scale   = (const float*)d_in[4];
    float*       out     = (float*)d_out;

    const int Hn = in_sizes[3];           // 128
    const int N  = in_sizes[0] / Hn;      // 1048576
    const int B  = in_sizes[1] / Hn;      // 1024

    const size_t sd_bytes  = (size_t)B * Hn * sizeof(float);   // 512 KB
    const size_t seg_bytes = (size_t)N * sizeof(int);          // 4 MB

    if (ws_size >= sd_bytes + seg_bytes) {
        float* sd  = (float*)d_ws;
        int*   seg = (int*)((char*)d_ws + sd_bytes);

        seg_fill<<<B, 256, 0, stream>>>(ptr, seg);
        const int sd_total = B * Hn;
        sd_fill<<<(sd_total + 255) / 256, 256, 0, stream>>>(summary, dvec,
                                                            scale, sd, sd_total);
        // 8 lanes/row, 256 threads -> 32 rows per block
        sim_main<<<(N + 31) / 32, 256, 0, stream>>>(emb, sd, seg, out, N);
    } else {
        sim_fallback<<<(N + 7) / 8, 256, 0, stream>>>(emb, summary, ptr, dvec,
                                                      scale, out, N, B);
    }
}